// Round 6
// baseline (222.379 us; speedup 1.0000x reference)
//
#include <hip/hip_runtime.h>
#include <hip/hip_bf16.h>
#include <math.h>

typedef __bf16 bf16_t;
typedef __bf16 bf16x4 __attribute__((ext_vector_type(4)));
typedef __bf16 bf16x8 __attribute__((ext_vector_type(8)));
typedef float  f32x4  __attribute__((ext_vector_type(4)));

static constexpr int S_LEN = 4096;
static constexpr int D_DIM = 64;
static constexpr int H_NUM = 16;
static constexpr int BT    = 64;
static constexpr float QSCALE = 0.18033688011112042f;  // (1/sqrt(64)) * log2(e)
static constexpr float MB2    = 12.0f;  // fixed softmax shift (base-2)

__device__ __forceinline__ float fexp2(float x) {
#if __has_builtin(__builtin_amdgcn_exp2f)
  return __builtin_amdgcn_exp2f(x);   // raw v_exp_f32 (r10-proven)
#else
  return exp2f(x);
#endif
}

// ---- prepack: VERBATIM from r10 (proven by r10's pass).
// K[h][d][s] f32 -> ktr[h][s][d] bf16 ; V[h][s][d] f32 -> vp[h][d][t'] bf16,
// t' = kt*32 + quad*8 + j  <->  t = kt*32 + (j>>2)*16 + quad*4 + (j&3).
__global__ __launch_bounds__(256)
void prepack(const float* __restrict__ kg, const float* __restrict__ vg,
             bf16_t* __restrict__ ktr, bf16_t* __restrict__ vpp) {
  __shared__ bf16_t tk[64][72];   // K^T tile [s][d]
  __shared__ bf16_t tv[64][72];   // V tile   [t][d]
  const int tid = threadIdx.x;
  const int h = blockIdx.x >> 6, sb = blockIdx.x & 63;
  const int s0 = sb * 64;
  const float* kh = kg + (size_t)h * D_DIM * S_LEN;
  const float* vh = vg + (size_t)h * S_LEN * D_DIM;

  #pragma unroll
  for (int it = 0; it < 4; ++it) {
    const int d = (tid >> 4) + it * 16;
    const int s = (tid & 15) * 4;
    const f32x4 x = *(const f32x4*)(kh + (size_t)d * S_LEN + s0 + s);  // K[d][s0+s..]
    #pragma unroll
    for (int i = 0; i < 4; ++i) tk[s + i][d] = (bf16_t)x[i];
    const f32x4 y = *(const f32x4*)(vh + (size_t)(s0 + d) * D_DIM + s); // V[s0+d][s..]
    bf16x4 yb;
    #pragma unroll
    for (int i = 0; i < 4; ++i) yb[i] = (bf16_t)y[i];
    *(bf16x4*)&tv[d][s] = yb;
  }
  __syncthreads();

  // K out: ktr[(h*S + s0+s)*64 + d]
  {
    const int s = tid >> 2, c = (tid & 3) * 16;
    const bf16x8 a = *(const bf16x8*)&tk[s][c];
    const bf16x8 b = *(const bf16x8*)&tk[s][c + 8];
    bf16_t* o = ktr + ((size_t)h * S_LEN + s0 + s) * D_DIM + c;
    *(bf16x8*)o = a;
    *(bf16x8*)(o + 8) = b;
  }
  // V out: vpp[(h*64 + d)*S + s0 + t'], permuted gather over tv columns
  {
    const int d = tid >> 2, g = (tid & 3) * 16;
    bf16x8 w0, w1;
    #pragma unroll
    for (int x = 0; x < 16; ++x) {
      const int tp = g + x;
      const int kt = tp >> 5, rem = tp & 31, qd = rem >> 3, j = rem & 7;
      const int t  = kt * 32 + (j >> 2) * 16 + qd * 4 + (j & 3);
      const bf16_t val = tv[t][d];
      if (x < 8) w0[x] = val; else w1[x - 8] = val;
    }
    bf16_t* o = vpp + ((size_t)h * D_DIM + d) * S_LEN + s0 + g;
    *(bf16x8*)o = w0;
    *(bf16x8*)(o + 8) = w1;
  }
}

// S^T flash attention, causal, fixed-max softmax. r16: LDS-BW diagnosis
// (r15: 80 KB LDS/step-work ~= 1200 of 1292 cy/step) -> V is removed from
// LDS entirely. The vp[h][d][t'] prepack layout makes each V MFMA fragment a
// contiguous bf16x8 in GLOBAL memory, so each lane loads its fragment
// directly (L2-resident, issued before QK^T so vmcnt is covered by
// QK^T+softmax). LDS traffic 80->40 KB/step-work; vT buffer, V staging and
// the whole vT write/read hazard class deleted. Fragments are 8 NAMED
// scalars (not an indexed array -- r11/r12's implicated construct).
// K path, barrier structure, and r15's balanced 4-way grid map unchanged.
__global__ __launch_bounds__(256, 4)
void attn_fwd(const float* __restrict__ qg, const bf16_t* __restrict__ ktr,
              const bf16_t* __restrict__ vpp, float* __restrict__ og) {
  __shared__ __align__(16) bf16_t kT[2][64][72];   // K^T tile [t][d]

  const int tid  = threadIdx.x;
  const int wave = tid >> 6;
  const int lane = tid & 63;
  const int col  = lane & 15;
  const int quad = lane >> 4;

  // r15 balanced 4-way grouping: co-resident jb=m(mod 16) -> qts
  // {63-m, m, 32+m, 31-m} = 130 steps per CU, heavy block first.
  const int h  = blockIdx.x & 15;
  const int jb = blockIdx.x >> 4;                  // 0..63
  const int m  = jb & 15;
  const int k4 = jb >> 4;                          // 0..3
  const int qt = (k4 == 0) ? (63 - m) : (k4 == 1) ? m : (k4 == 2) ? (32 + m) : (31 - m);
  const int qbase = qt * 64;

  const float*  qh  = qg  + (size_t)h * S_LEN * D_DIM;
  const bf16_t* kth = ktr + (size_t)h * S_LEN * D_DIM;   // [s][d]
  const bf16_t* vph = vpp + (size_t)h * D_DIM * S_LEN;   // [d][t'_global]
  float*        oh  = og  + (size_t)h * S_LEN * D_DIM;

  const int wr0 = qbase + wave * 16;   // this wave's 16 q-rows

  // staging mapping: thread copies 16 elems of one K row (st = row, sc = col)
  const int st = tid >> 2;             // t-local 0..63
  const int sc = (tid & 3) * 16;       // 0,16,32,48

  // ---- Q^T B-fragments (r8-proven, rt dim removed) ----
  bf16x8 qb[2];
  {
    const float* qp = qh + (size_t)(wr0 + col) * D_DIM;
    #pragma unroll
    for (int kk = 0; kk < 2; ++kk) {
      f32x4 lo = *(const f32x4*)(qp + kk * 32 + quad * 8);
      f32x4 hi = *(const f32x4*)(qp + kk * 32 + quad * 8 + 4);
      #pragma unroll
      for (int j = 0; j < 4; ++j) {
        qb[kk][j]     = (bf16_t)(lo[j] * QSCALE);
        qb[kk][j + 4] = (bf16_t)(hi[j] * QSCALE);
      }
    }
  }

  f32x4 acc[4];
  #pragma unroll
  for (int nt = 0; nt < 4; ++nt) acc[nt] = (f32x4){0.f, 0.f, 0.f, 0.f};
  float l_i = 0.f;

  const int nsteps = qt + 1;

  // per-lane V fragment base: vph[d = nt*16+col][t' = t0 + kt*32 + quad*8]
  const bf16_t* vbase = vph + (size_t)col * S_LEN + quad * 8;

  // ---- prologue: stage K tile 0 into buffer 0 ----
  {
    const bf16_t* kp = kth + (size_t)st * 64 + sc;
    *(bf16x8*)&kT[0][st][sc]     = *(const bf16x8*)kp;
    *(bf16x8*)&kT[0][st][sc + 8] = *(const bf16x8*)(kp + 8);
  }
  __syncthreads();

  for (int s = 0; s < nsteps; ++s) {
    const int buf = s & 1;
    const int t0  = s * BT;
    const bool pf = (s + 1 < nsteps);

    // ---- K fragments (r8-proven padded reads) ----
    bf16x8 kf[4][2];
    #pragma unroll
    for (int ct = 0; ct < 4; ++ct)
      #pragma unroll
      for (int kk = 0; kk < 2; ++kk)
        kf[ct][kk] = *(const bf16x8*)&kT[buf][ct * 16 + col][kk * 32 + quad * 8];

    // ---- V fragments DIRECT FROM GLOBAL (r16), issued early: vmcnt
    // covered by QK^T+softmax. 8 named scalars, no array indexing. ----
    const bf16_t* vb = vbase + t0;
    const bf16x8 vf00 = *(const bf16x8*)(vb);
    const bf16x8 vf01 = *(const bf16x8*)(vb + 16 * S_LEN);
    const bf16x8 vf02 = *(const bf16x8*)(vb + 32 * S_LEN);
    const bf16x8 vf03 = *(const bf16x8*)(vb + 48 * S_LEN);
    const bf16x8 vf10 = *(const bf16x8*)(vb + 32);
    const bf16x8 vf11 = *(const bf16x8*)(vb + 32 + 16 * S_LEN);
    const bf16x8 vf12 = *(const bf16x8*)(vb + 32 + 32 * S_LEN);
    const bf16x8 vf13 = *(const bf16x8*)(vb + 32 + 48 * S_LEN);

    // ---- K prefetch issue, early (r13-proven) ----
    bf16x8 kp0, kp1;
    if (pf) {
      const bf16_t* kp = kth + (size_t)(t0 + BT + st) * 64 + sc;
      kp0 = *(const bf16x8*)kp;
      kp1 = *(const bf16x8*)(kp + 8);
    }

    // ---- QK^T -> S^T (C init -MB2) ----
    f32x4 sc_[4];
    #pragma unroll
    for (int ct = 0; ct < 4; ++ct) sc_[ct] = (f32x4){-MB2, -MB2, -MB2, -MB2};
    __builtin_amdgcn_s_setprio(1);
    #pragma unroll
    for (int ct = 0; ct < 4; ++ct)
      #pragma unroll
      for (int kk = 0; kk < 2; ++kk)
        sc_[ct] = __builtin_amdgcn_mfma_f32_16x16x32_bf16(kf[ct][kk], qb[kk], sc_[ct], 0, 0, 0);
    __builtin_amdgcn_s_setprio(0);

    // ---- fixed-max softmax -> PV B-fragments in registers (r8-proven) ----
    bf16x8 pfrag[2];
    {
      const int qrow = wr0 + col;
      if (t0 + BT - 1 > wr0) {   // diagonal step: mask
        #pragma unroll
        for (int ct = 0; ct < 4; ++ct)
          #pragma unroll
          for (int r = 0; r < 4; ++r)
            sc_[ct][r] = (t0 + ct * 16 + quad * 4 + r > qrow) ? -1e30f : sc_[ct][r];
      }
      float rs0 = 0.f, rs1 = 0.f;
      #pragma unroll
      for (int ct = 0; ct < 4; ++ct) {
        const float p0 = fexp2(sc_[ct][0]);
        const float p1 = fexp2(sc_[ct][1]);
        const float p2 = fexp2(sc_[ct][2]);
        const float p3 = fexp2(sc_[ct][3]);
        rs0 += p0 + p1; rs1 += p2 + p3;
        const int kt = ct >> 1, hh = (ct & 1) * 4;
        pfrag[kt][hh + 0] = (bf16_t)p0;
        pfrag[kt][hh + 1] = (bf16_t)p1;
        pfrag[kt][hh + 2] = (bf16_t)p2;
        pfrag[kt][hh + 3] = (bf16_t)p3;
      }
      l_i += rs0 + rs1;
    }

    // ---- stage prefetched K into buf^1 ----
    if (pf) {
      *(bf16x8*)&kT[buf ^ 1][st][sc]     = kp0;
      *(bf16x8*)&kT[buf ^ 1][st][sc + 8] = kp1;
    }

    // ---- PV -> O^T (A = V^T global regs, B = pfrag registers) ----
    __builtin_amdgcn_s_setprio(1);
    acc[0] = __builtin_amdgcn_mfma_f32_16x16x32_bf16(vf00, pfrag[0], acc[0], 0, 0, 0);
    acc[1] = __builtin_amdgcn_mfma_f32_16x16x32_bf16(vf01, pfrag[0], acc[1], 0, 0, 0);
    acc[2] = __builtin_amdgcn_mfma_f32_16x16x32_bf16(vf02, pfrag[0], acc[2], 0, 0, 0);
    acc[3] = __builtin_amdgcn_mfma_f32_16x16x32_bf16(vf03, pfrag[0], acc[3], 0, 0, 0);
    acc[0] = __builtin_amdgcn_mfma_f32_16x16x32_bf16(vf10, pfrag[1], acc[0], 0, 0, 0);
    acc[1] = __builtin_amdgcn_mfma_f32_16x16x32_bf16(vf11, pfrag[1], acc[1], 0, 0, 0);
    acc[2] = __builtin_amdgcn_mfma_f32_16x16x32_bf16(vf12, pfrag[1], acc[2], 0, 0, 0);
    acc[3] = __builtin_amdgcn_mfma_f32_16x16x32_bf16(vf13, pfrag[1], acc[3], 0, 0, 0);
    __builtin_amdgcn_s_setprio(0);

    __syncthreads();   // the ONLY barrier per step (protects kT)
  }

  // ---- epilogue: reduce l across quads, normalize, store (r8-proven) ----
  {
    float l = l_i;
    l += __shfl_xor(l, 16);
    l += __shfl_xor(l, 32);
    const float inv_l = 1.0f / l;
    const int qr = wr0 + col;
    float* op = oh + (size_t)qr * D_DIM + quad * 4;
    #pragma unroll
    for (int nt = 0; nt < 4; ++nt) {
      f32x4 o;
      o[0] = acc[nt][0] * inv_l; o[1] = acc[nt][1] * inv_l;
      o[2] = acc[nt][2] * inv_l; o[3] = acc[nt][3] * inv_l;
      *(f32x4*)(op + nt * 16) = o;
    }
  }
}

extern "C" void kernel_launch(void* const* d_in, const int* in_sizes, int n_in,
                              void* d_out, int out_size, void* d_ws, size_t ws_size,
                              hipStream_t stream) {
  const float* q = (const float*)d_in[0];
  const float* k = (const float*)d_in[1];
  const float* v = (const float*)d_in[2];
  float* out = (float*)d_out;

  // ws: [0,8M) ktr bf16 | [8M,16M) vp bf16 -> exactly 16 MB (r10-proven budget)
  const size_t KB = (size_t)H_NUM * S_LEN * D_DIM * 2;   // 8,388,608
  bf16_t* ktr = (bf16_t*)d_ws;
  bf16_t* vp  = (bf16_t*)((char*)d_ws + KB);

  dim3 block(256);
  prepack<<<dim3(H_NUM * 64), block, 0, stream>>>(k, v, ktr, vp);
  attn_fwd<<<dim3(H_NUM * 64), block, 0, stream>>>(q, ktr, vp, out);
}

// Round 7
// 144.492 us; speedup vs baseline: 1.5390x; 1.5390x over previous
//
#include <hip/hip_runtime.h>
#include <hip/hip_bf16.h>
#include <math.h>

typedef __bf16 bf16_t;
typedef __bf16 bf16x4 __attribute__((ext_vector_type(4)));
typedef __bf16 bf16x8 __attribute__((ext_vector_type(8)));
typedef float  f32x4  __attribute__((ext_vector_type(4)));

static constexpr int S_LEN = 4096;
static constexpr int D_DIM = 64;
static constexpr int H_NUM = 16;
static constexpr int BT    = 64;
static constexpr float QSCALE = 0.18033688011112042f;  // (1/sqrt(64)) * log2(e)
static constexpr float MB2    = 12.0f;  // fixed softmax shift (base-2)

__device__ __forceinline__ float fexp2(float x) {
#if __has_builtin(__builtin_amdgcn_exp2f)
  return __builtin_amdgcn_exp2f(x);   // raw v_exp_f32 (r10-proven)
#else
  return exp2f(x);
#endif
}

// ---- prepack (r17): K path VERBATIM from r10. V is emitted in
// FRAGMENT-ORDER: vq[((h*64+ts)*8 + f)*512 + lane*8 + j], f = kt*4+nt,
// holding value V^T[d = nt*16+(lane&15)][t = kt*32+(j>>2)*16+(lane>>4)*4+(j&3)]
// of kv-tile ts. In attn, vf(kt,nt) = load at base + f*1024B + lane*16B ->
// one fully-coalesced 1KB transaction per fragment (fixes r16's 16-line
// gather). Values identical to r16's (which passed); only addresses moved.
__global__ __launch_bounds__(256)
void prepack(const float* __restrict__ kg, const float* __restrict__ vg,
             bf16_t* __restrict__ ktr, bf16_t* __restrict__ vq) {
  __shared__ bf16_t tk[64][72];   // K^T tile [s][d]
  __shared__ bf16_t tv[64][72];   // V tile   [t][d]
  const int tid = threadIdx.x;
  const int h = blockIdx.x >> 6, sb = blockIdx.x & 63;
  const int s0 = sb * 64;
  const float* kh = kg + (size_t)h * D_DIM * S_LEN;
  const float* vh = vg + (size_t)h * S_LEN * D_DIM;

  #pragma unroll
  for (int it = 0; it < 4; ++it) {
    const int d = (tid >> 4) + it * 16;
    const int s = (tid & 15) * 4;
    const f32x4 x = *(const f32x4*)(kh + (size_t)d * S_LEN + s0 + s);  // K[d][s0+s..]
    #pragma unroll
    for (int i = 0; i < 4; ++i) tk[s + i][d] = (bf16_t)x[i];
    const f32x4 y = *(const f32x4*)(vh + (size_t)(s0 + d) * D_DIM + s); // V[s0+d][s..]
    bf16x4 yb;
    #pragma unroll
    for (int i = 0; i < 4; ++i) yb[i] = (bf16_t)y[i];
    *(bf16x4*)&tv[d][s] = yb;
  }
  __syncthreads();

  // K out: ktr[(h*S + s0+s)*64 + d]  (unchanged, r10-proven)
  {
    const int s = tid >> 2, c = (tid & 3) * 16;
    const bf16x8 a = *(const bf16x8*)&tk[s][c];
    const bf16x8 b = *(const bf16x8*)&tk[s][c + 8];
    bf16_t* o = ktr + ((size_t)h * S_LEN + s0 + s) * D_DIM + c;
    *(bf16x8*)o = a;
    *(bf16x8*)(o + 8) = b;
  }
  // V out, fragment-order (r17): thread tid -> frag f = tid>>5, two lanes.
  {
    const int f  = tid >> 5;          // 0..7
    const int kt = f >> 2, nt = f & 3;
    const int l0 = (tid & 31) * 2;    // lanes l0, l0+1
    #pragma unroll
    for (int li = 0; li < 2; ++li) {
      const int l = l0 + li;
      const int colv = l & 15, quadv = l >> 4;
      const int d = nt * 16 + colv;
      bf16x8 w;
      #pragma unroll
      for (int j = 0; j < 8; ++j) {
        const int t = kt * 32 + (j >> 2) * 16 + quadv * 4 + (j & 3);
        w[j] = tv[t][d];
      }
      *(bf16x8*)(vq + (((size_t)(h * 64 + sb) * 8 + f) * 512 + l * 8)) = w;
    }
  }
}

// S^T flash attention, causal, fixed-max softmax. r17 = r16 structure
// (K in LDS double-buffered, V direct from global, no vT buffer, one
// barrier/step, r15 balanced 4-way grid: co-resident jb=m(mod16) -> qts
// {63-m, m, 32+m, 31-m} = 130 steps/CU) with the V loads now COALESCED
// via the fragment-order prepack: vf(kt,nt) = 1KB contiguous per wave.
__global__ __launch_bounds__(256, 4)
void attn_fwd(const float* __restrict__ qg, const bf16_t* __restrict__ ktr,
              const bf16_t* __restrict__ vq, float* __restrict__ og) {
  __shared__ __align__(16) bf16_t kT[2][64][72];   // K^T tile [t][d]

  const int tid  = threadIdx.x;
  const int wave = tid >> 6;
  const int lane = tid & 63;
  const int col  = lane & 15;
  const int quad = lane >> 4;

  const int h  = blockIdx.x & 15;
  const int jb = blockIdx.x >> 4;                  // 0..63
  const int m  = jb & 15;
  const int k4 = jb >> 4;                          // 0..3
  const int qt = (k4 == 0) ? (63 - m) : (k4 == 1) ? m : (k4 == 2) ? (32 + m) : (31 - m);
  const int qbase = qt * 64;

  const float*  qh  = qg  + (size_t)h * S_LEN * D_DIM;
  const bf16_t* kth = ktr + (size_t)h * S_LEN * D_DIM;   // [s][d]
  const bf16_t* vqh = vq  + (size_t)h * 64 * 8 * 512;    // [ts][f][lane][8]
  float*        oh  = og  + (size_t)h * S_LEN * D_DIM;

  const int wr0 = qbase + wave * 16;   // this wave's 16 q-rows

  // staging mapping: thread copies 16 elems of one K row (st = row, sc = col)
  const int st = tid >> 2;             // t-local 0..63
  const int sc = (tid & 3) * 16;       // 0,16,32,48

  // ---- Q^T B-fragments (r8-proven) ----
  bf16x8 qb[2];
  {
    const float* qp = qh + (size_t)(wr0 + col) * D_DIM;
    #pragma unroll
    for (int kk = 0; kk < 2; ++kk) {
      f32x4 lo = *(const f32x4*)(qp + kk * 32 + quad * 8);
      f32x4 hi = *(const f32x4*)(qp + kk * 32 + quad * 8 + 4);
      #pragma unroll
      for (int j = 0; j < 4; ++j) {
        qb[kk][j]     = (bf16_t)(lo[j] * QSCALE);
        qb[kk][j + 4] = (bf16_t)(hi[j] * QSCALE);
      }
    }
  }

  f32x4 acc[4];
  #pragma unroll
  for (int nt = 0; nt < 4; ++nt) acc[nt] = (f32x4){0.f, 0.f, 0.f, 0.f};
  float l_i = 0.f;

  const int nsteps = qt + 1;

  // per-lane V fragment base (fragment-order): + ts*4096 + f*512 + lane*8
  const bf16_t* vbase = vqh + (size_t)lane * 8;

  // ---- prologue: stage K tile 0 into buffer 0 ----
  {
    const bf16_t* kp = kth + (size_t)st * 64 + sc;
    *(bf16x8*)&kT[0][st][sc]     = *(const bf16x8*)kp;
    *(bf16x8*)&kT[0][st][sc + 8] = *(const bf16x8*)(kp + 8);
  }
  __syncthreads();

  for (int s = 0; s < nsteps; ++s) {
    const int buf = s & 1;
    const int t0  = s * BT;
    const bool pf = (s + 1 < nsteps);

    // ---- K fragments (r8-proven padded reads) ----
    bf16x8 kf[4][2];
    #pragma unroll
    for (int ct = 0; ct < 4; ++ct)
      #pragma unroll
      for (int kk = 0; kk < 2; ++kk)
        kf[ct][kk] = *(const bf16x8*)&kT[buf][ct * 16 + col][kk * 32 + quad * 8];

    // ---- V fragments from global, COALESCED (r17): 8 named 1KB-coalesced
    // loads, issued early so vmcnt is covered by QK^T+softmax ----
    const bf16_t* vb = vbase + (size_t)s * 4096;
    const bf16x8 vf00 = *(const bf16x8*)(vb);
    const bf16x8 vf01 = *(const bf16x8*)(vb + 512);
    const bf16x8 vf02 = *(const bf16x8*)(vb + 1024);
    const bf16x8 vf03 = *(const bf16x8*)(vb + 1536);
    const bf16x8 vf10 = *(const bf16x8*)(vb + 2048);
    const bf16x8 vf11 = *(const bf16x8*)(vb + 2560);
    const bf16x8 vf12 = *(const bf16x8*)(vb + 3072);
    const bf16x8 vf13 = *(const bf16x8*)(vb + 3584);

    // ---- K prefetch issue, early (r13-proven) ----
    bf16x8 kp0, kp1;
    if (pf) {
      const bf16_t* kp = kth + (size_t)(t0 + BT + st) * 64 + sc;
      kp0 = *(const bf16x8*)kp;
      kp1 = *(const bf16x8*)(kp + 8);
    }

    // ---- QK^T -> S^T (C init -MB2) ----
    f32x4 sc_[4];
    #pragma unroll
    for (int ct = 0; ct < 4; ++ct) sc_[ct] = (f32x4){-MB2, -MB2, -MB2, -MB2};
    __builtin_amdgcn_s_setprio(1);
    #pragma unroll
    for (int ct = 0; ct < 4; ++ct)
      #pragma unroll
      for (int kk = 0; kk < 2; ++kk)
        sc_[ct] = __builtin_amdgcn_mfma_f32_16x16x32_bf16(kf[ct][kk], qb[kk], sc_[ct], 0, 0, 0);
    __builtin_amdgcn_s_setprio(0);

    // ---- fixed-max softmax -> PV B-fragments in registers (r8-proven) ----
    bf16x8 pfrag[2];
    {
      const int qrow = wr0 + col;
      if (t0 + BT - 1 > wr0) {   // diagonal step: mask
        #pragma unroll
        for (int ct = 0; ct < 4; ++ct)
          #pragma unroll
          for (int r = 0; r < 4; ++r)
            sc_[ct][r] = (t0 + ct * 16 + quad * 4 + r > qrow) ? -1e30f : sc_[ct][r];
      }
      float rs0 = 0.f, rs1 = 0.f;
      #pragma unroll
      for (int ct = 0; ct < 4; ++ct) {
        const float p0 = fexp2(sc_[ct][0]);
        const float p1 = fexp2(sc_[ct][1]);
        const float p2 = fexp2(sc_[ct][2]);
        const float p3 = fexp2(sc_[ct][3]);
        rs0 += p0 + p1; rs1 += p2 + p3;
        const int kt = ct >> 1, hh = (ct & 1) * 4;
        pfrag[kt][hh + 0] = (bf16_t)p0;
        pfrag[kt][hh + 1] = (bf16_t)p1;
        pfrag[kt][hh + 2] = (bf16_t)p2;
        pfrag[kt][hh + 3] = (bf16_t)p3;
      }
      l_i += rs0 + rs1;
    }

    // ---- stage prefetched K into buf^1 ----
    if (pf) {
      *(bf16x8*)&kT[buf ^ 1][st][sc]     = kp0;
      *(bf16x8*)&kT[buf ^ 1][st][sc + 8] = kp1;
    }

    // ---- PV -> O^T (A = V^T global regs, B = pfrag registers) ----
    __builtin_amdgcn_s_setprio(1);
    acc[0] = __builtin_amdgcn_mfma_f32_16x16x32_bf16(vf00, pfrag[0], acc[0], 0, 0, 0);
    acc[1] = __builtin_amdgcn_mfma_f32_16x16x32_bf16(vf01, pfrag[0], acc[1], 0, 0, 0);
    acc[2] = __builtin_amdgcn_mfma_f32_16x16x32_bf16(vf02, pfrag[0], acc[2], 0, 0, 0);
    acc[3] = __builtin_amdgcn_mfma_f32_16x16x32_bf16(vf03, pfrag[0], acc[3], 0, 0, 0);
    acc[0] = __builtin_amdgcn_mfma_f32_16x16x32_bf16(vf10, pfrag[1], acc[0], 0, 0, 0);
    acc[1] = __builtin_amdgcn_mfma_f32_16x16x32_bf16(vf11, pfrag[1], acc[1], 0, 0, 0);
    acc[2] = __builtin_amdgcn_mfma_f32_16x16x32_bf16(vf12, pfrag[1], acc[2], 0, 0, 0);
    acc[3] = __builtin_amdgcn_mfma_f32_16x16x32_bf16(vf13, pfrag[1], acc[3], 0, 0, 0);
    __builtin_amdgcn_s_setprio(0);

    __syncthreads();   // the ONLY barrier per step (protects kT)
  }

  // ---- epilogue: reduce l across quads, normalize, store (r8-proven) ----
  {
    float l = l_i;
    l += __shfl_xor(l, 16);
    l += __shfl_xor(l, 32);
    const float inv_l = 1.0f / l;
    const int qr = wr0 + col;
    float* op = oh + (size_t)qr * D_DIM + quad * 4;
    #pragma unroll
    for (int nt = 0; nt < 4; ++nt) {
      f32x4 o;
      o[0] = acc[nt][0] * inv_l; o[1] = acc[nt][1] * inv_l;
      o[2] = acc[nt][2] * inv_l; o[3] = acc[nt][3] * inv_l;
      *(f32x4*)(op + nt * 16) = o;
    }
  }
}

extern "C" void kernel_launch(void* const* d_in, const int* in_sizes, int n_in,
                              void* d_out, int out_size, void* d_ws, size_t ws_size,
                              hipStream_t stream) {
  const float* q = (const float*)d_in[0];
  const float* k = (const float*)d_in[1];
  const float* v = (const float*)d_in[2];
  float* out = (float*)d_out;

  // ws: [0,8M) ktr bf16 | [8M,16M) vq bf16 (fragment-order) -> 16 MB
  const size_t KB = (size_t)H_NUM * S_LEN * D_DIM * 2;   // 8,388,608
  bf16_t* ktr = (bf16_t*)d_ws;
  bf16_t* vq  = (bf16_t*)((char*)d_ws + KB);

  dim3 block(256);
  prepack<<<dim3(H_NUM * 64), block, 0, stream>>>(k, v, ktr, vq);
  attn_fwd<<<dim3(H_NUM * 64), block, 0, stream>>>(q, ktr, vq, out);
}